// Round 7
// baseline (238.184 us; speedup 1.0000x reference)
//
#include <hip/hip_runtime.h>
#include <hip/hip_bf16.h>

// Problem constants (from reference)
#define NN 2048
#define TT 64
#define EE 16384
#define BB 64
#define K0C 32
#define EMBC 128
#define K1C 64
#define K2C 64
#define KSZ 7
#define POOLK 4
#define BNEPS 1e-5f

typedef __attribute__((ext_vector_type(8))) short short8;     // 8 bf16 (4 VGPRs)
typedef __attribute__((ext_vector_type(16))) float floatx16;  // 32x32 MFMA C/D frag

// float -> bf16 bits, round-to-nearest-even
static __device__ __forceinline__ unsigned short f2bf(float f) {
    unsigned int u = __float_as_uint(f);
    u += 0x7fffu + ((u >> 16) & 1u);
    return (unsigned short)(u >> 16);
}
static __device__ __forceinline__ float bflo(unsigned int u) { return __uint_as_float(u << 16); }
static __device__ __forceinline__ float bfhi(unsigned int u) { return __uint_as_float(u & 0xffff0000u); }

static __device__ __forceinline__ void unpack8(uint4 r, float w, float* acc) {
    acc[0] += w * bflo(r.x); acc[1] += w * bfhi(r.x);
    acc[2] += w * bflo(r.y); acc[3] += w * bfhi(r.y);
    acc[4] += w * bflo(r.z); acc[5] += w * bfhi(r.z);
    acc[6] += w * bflo(r.w); acc[7] += w * bfhi(r.w);
}
static __device__ __forceinline__ uint4 pack8(const float* a) {
    uint4 r;
    r.x = (unsigned int)f2bf(a[0]) | ((unsigned int)f2bf(a[1]) << 16);
    r.y = (unsigned int)f2bf(a[2]) | ((unsigned int)f2bf(a[3]) << 16);
    r.z = (unsigned int)f2bf(a[4]) | ((unsigned int)f2bf(a[5]) << 16);
    r.w = (unsigned int)f2bf(a[6]) | ((unsigned int)f2bf(a[7]) << 16);
    return r;
}

// ---------------------------------------------------------------------------
// Graph preprocessing
// ---------------------------------------------------------------------------
__global__ void count_deg_kernel(const int* __restrict__ ei, int* __restrict__ deg) {
    int e = blockIdx.x * 256 + threadIdx.x;
    if (e < EE) atomicAdd(&deg[ei[EE + e]], 1);   // dst = second row
}

__global__ void dinv_kernel(const int* __restrict__ deg, float* __restrict__ dinv) {
    int n = blockIdx.x * 256 + threadIdx.x;
    if (n < NN) dinv[n] = rsqrtf((float)deg[n] + 1.0f);   // +1 self loop
}

__global__ void scan_kernel(const int* __restrict__ deg, int* __restrict__ row_start) {
    __shared__ int tsum[256];
    int tid = threadIdx.x;
    int loc[8];
    int s = 0;
#pragma unroll
    for (int i = 0; i < 8; ++i) { loc[i] = s; s += deg[tid * 8 + i]; }
    tsum[tid] = s;
    __syncthreads();
    for (int off = 1; off < 256; off <<= 1) {
        int v = (tid >= off) ? tsum[tid - off] : 0;
        __syncthreads();
        tsum[tid] += v;
        __syncthreads();
    }
    int base = (tid > 0) ? tsum[tid - 1] : 0;
#pragma unroll
    for (int i = 0; i < 8; ++i) row_start[tid * 8 + i] = base + loc[i];
    if (tid == 255) row_start[NN] = tsum[255];
}

__global__ void fill_csr_kernel(const int* __restrict__ ei, const int* __restrict__ row_start,
                                int* __restrict__ cursor, const float* __restrict__ dinv,
                                int* __restrict__ csr_src, float* __restrict__ csr_norm) {
    int e = blockIdx.x * 256 + threadIdx.x;
    if (e >= EE) return;
    int s = ei[e];
    int d = ei[EE + e];
    int pos = row_start[d] + atomicAdd(&cursor[d], 1);
    csr_src[pos] = s;
    csr_norm[pos] = dinv[s] * dinv[d];
}

// ---------------------------------------------------------------------------
// Weight prep: transpose + cast to bf16.
// ---------------------------------------------------------------------------
__global__ void prep_weights_kernel(const float* __restrict__ g1w, const float* __restrict__ g2w,
                                    const float* __restrict__ c2w,
                                    unsigned short* __restrict__ Wt1,
                                    unsigned short* __restrict__ Wt2,
                                    unsigned short* __restrict__ Bt) {
    int idx = blockIdx.x * 256 + threadIdx.x;
    if (idx < 4096) {
        int d = idx >> 5, k = idx & 31;
        Wt1[idx] = f2bf(g1w[k * 128 + d]);
    } else if (idx < 20480) {
        int j = idx - 4096;
        int d = j >> 7, k = j & 127;
        Wt2[j] = f2bf(g2w[k * 128 + d]);
    } else if (idx < 77824) {
        int j = idx - 20480;
        int c = j / 896, k = j % 896;
        Bt[j] = f2bf(c2w[k * 64 + c]);
    }
}

// ---------------------------------------------------------------------------
// conv1 (SAME, 1->32) + bn1 + relu : x (N,T) -> h0t bf16 (T, N, 32)
// ---------------------------------------------------------------------------
__global__ void conv1_bn_relu_kernel(const float* __restrict__ x, const float* __restrict__ w,
                                     const float* __restrict__ g, const float* __restrict__ b,
                                     const float* __restrict__ m, const float* __restrict__ v,
                                     unsigned short* __restrict__ h0t) {
    int idx = blockIdx.x * 256 + threadIdx.x;      // (t*2048 + n)*32 + c
    int c = idx & 31;
    int n = (idx >> 5) & 2047;
    int t = idx >> 16;
    float acc = 0.f;
#pragma unroll
    for (int k = 0; k < KSZ; ++k) {
        int tt = t + k - 3;
        if (tt >= 0 && tt < TT) acc += x[n * TT + tt] * w[k * K0C + c];
    }
    float scale = g[c] * rsqrtf(v[c] + BNEPS);
    float val = (acc - m[c]) * scale + b[c];
    h0t[idx] = f2bf(fmaxf(val, 0.f));              // coalesced in (T,N,32)
}

// ---------------------------------------------------------------------------
// GCN layer 1, t-sliced: block = (t, 128 dst). Edges staged in LDS, gather
// 4-deep software-pipelined (2 thr/dst, 32B each) -> LDS -> MFMA -> h1t.
// ---------------------------------------------------------------------------
__global__ __launch_bounds__(256, 4) void gcn1_t_kernel(
        const unsigned short* __restrict__ h0t, const unsigned short* __restrict__ Wt,
        const float* __restrict__ bias, unsigned short* __restrict__ h1t,
        const int* __restrict__ row_start, const int* __restrict__ csr_src,
        const float* __restrict__ csr_norm, const float* __restrict__ dinv) {
    constexpr int STRIDE = 40;
    constexpr int CAP = 2048;
    __shared__ __align__(16) unsigned short sAgg[128 * STRIDE];
    __shared__ int s_src[CAP];
    __shared__ float s_w[CAP];
    const int b = blockIdx.x;                 // 1024 blocks = 64 t x 16 groups
    const int xcd = b & 7;
    const int idx = b >> 3;
    const int t = xcd * 8 + (idx >> 4);
    const int g = idx & 15;
    const int n0 = g * 128;
    const int tid = threadIdx.x;
    const int sub = tid >> 1;                 // dst 0..127
    const int half = tid & 1;                 // 16-channel half
    const int n = n0 + sub;

    const unsigned short* base = h0t + (size_t)t * (NN * K0C);
    int rs = row_start[n], re = row_start[n + 1];
    int rs_blk = row_start[n0], re_blk = row_start[n0 + 128];
    float dn = dinv[n];
    float selfw = dn * dn;
    float acc[16];
#pragma unroll
    for (int i = 0; i < 16; ++i) acc[i] = 0.f;
    {
        const uint4* p = (const uint4*)(base + n * K0C + half * 16);
        uint4 r0 = p[0], r1 = p[1];
        unpack8(r0, selfw, acc); unpack8(r1, selfw, acc + 8);
    }
#define LD_G1(s0, s1, J) { int ssrc = s_src[o + (J)]; \
    const uint4* pp = (const uint4*)(base + ssrc * K0C + half * 16); \
    s0 = pp[0]; s1 = pp[1]; }
    for (int cbase = rs_blk; cbase < re_blk; cbase += CAP) {
        int cnt = min(CAP, re_blk - cbase);
        __syncthreads();
        for (int i = tid; i < cnt; i += 256) {
            s_src[i] = csr_src[cbase + i];
            s_w[i] = csr_norm[cbase + i];
        }
        __syncthreads();
        int a = max(rs, cbase), bb = min(re, cbase + cnt);
        int m = bb - a, o = a - cbase;
        uint4 p00, p01, p10, p11, p20, p21, p30, p31;
        if (m > 0) LD_G1(p00, p01, 0);
        if (m > 1) LD_G1(p10, p11, 1);
        if (m > 2) LD_G1(p20, p21, 2);
        if (m > 3) LD_G1(p30, p31, 3);
        int j = 0;
        while (j + 4 <= m) {
            float w0 = s_w[o + j], w1 = s_w[o + j + 1];
            float w2 = s_w[o + j + 2], w3 = s_w[o + j + 3];
            uint4 c00 = p00, c01 = p01, c10 = p10, c11 = p11;
            uint4 c20 = p20, c21 = p21, c30 = p30, c31 = p31;
            if (j + 4 < m) LD_G1(p00, p01, j + 4);
            if (j + 5 < m) LD_G1(p10, p11, j + 5);
            if (j + 6 < m) LD_G1(p20, p21, j + 6);
            if (j + 7 < m) LD_G1(p30, p31, j + 7);
            unpack8(c00, w0, acc); unpack8(c01, w0, acc + 8);
            unpack8(c10, w1, acc); unpack8(c11, w1, acc + 8);
            unpack8(c20, w2, acc); unpack8(c21, w2, acc + 8);
            unpack8(c30, w3, acc); unpack8(c31, w3, acc + 8);
            j += 4;
        }
        if (j < m) { float w = s_w[o + j]; unpack8(p00, w, acc); unpack8(p01, w, acc + 8); ++j; }
        if (j < m) { float w = s_w[o + j]; unpack8(p10, w, acc); unpack8(p11, w, acc + 8); ++j; }
        if (j < m) { float w = s_w[o + j]; unpack8(p20, w, acc); unpack8(p21, w, acc + 8); ++j; }
    }
#undef LD_G1
    *(uint4*)&sAgg[sub * STRIDE + half * 16] = pack8(acc);
    *(uint4*)&sAgg[sub * STRIDE + half * 16 + 8] = pack8(acc + 8);
    __syncthreads();

    // MFMA (128x32)@(32x128): wave = 32 rows, 4 col-tiles
    const int wave = tid >> 6;
    const int lane = tid & 63;
    const int l31 = lane & 31;
    const int q = lane >> 5;
    floatx16 accv[4];
#pragma unroll
    for (int ct = 0; ct < 4; ++ct) accv[ct] = (floatx16)0.f;
#pragma unroll
    for (int kk = 0; kk < 2; ++kk) {
        short8 av = *(const short8*)&sAgg[(32 * wave + l31) * STRIDE + kk * 16 + q * 8];
#pragma unroll
        for (int ct = 0; ct < 4; ++ct) {
            short8 bb = *(const short8*)(Wt + (size_t)(32 * ct + l31) * K0C + kk * 16 + q * 8);
            accv[ct] = __builtin_amdgcn_mfma_f32_32x32x16_bf16(av, bb, accv[ct], 0, 0, 0);
        }
    }
    unsigned short* orow = h1t + ((size_t)t * NN + n0) * EMBC;
#pragma unroll
    for (int ct = 0; ct < 4; ++ct) {
        int col = 32 * ct + l31;
        float bv = bias[col];
#pragma unroll
        for (int r = 0; r < 16; ++r) {
            int row = 32 * wave + (r & 3) + 8 * (r >> 2) + 4 * q;
            orow[row * EMBC + col] = f2bf(fmaxf(accv[ct][r] + bv, 0.f));
        }
    }
}

// ---------------------------------------------------------------------------
// GCN layer 2, t-sliced: block = (t, 32 dst). Edges staged in LDS, gather
// 4-deep software-pipelined (8 thr/dst, 32B each) -> LDS -> MFMA -> h2 (N,T,C).
// ---------------------------------------------------------------------------
__global__ __launch_bounds__(256, 4) void gcn2_t_kernel(
        const unsigned short* __restrict__ h1t, const unsigned short* __restrict__ Wt,
        const float* __restrict__ bias, unsigned short* __restrict__ h2,
        const int* __restrict__ row_start, const int* __restrict__ csr_src,
        const float* __restrict__ csr_norm, const float* __restrict__ dinv) {
    constexpr int STRIDE = 136;
    constexpr int CAP = 1024;
    __shared__ __align__(16) unsigned short sAgg[32 * STRIDE];
    __shared__ int s_src[CAP];
    __shared__ float s_w[CAP];
    const int b = blockIdx.x;                 // 4096 blocks = 64 t x 64 groups
    const int xcd = b & 7;
    const int idx = b >> 3;
    const int t = xcd * 8 + (idx >> 6);
    const int g = idx & 63;
    const int n0 = g * 32;
    const int tid = threadIdx.x;
    const int sub = tid >> 3;                 // dst 0..31
    const int part = tid & 7;                 // 16-channel part
    const int n = n0 + sub;

    const unsigned short* base = h1t + (size_t)t * (NN * EMBC);
    int rs = row_start[n], re = row_start[n + 1];
    int rs_blk = row_start[n0], re_blk = row_start[n0 + 32];
    float dn = dinv[n];
    float selfw = dn * dn;
    float acc[16];
#pragma unroll
    for (int i = 0; i < 16; ++i) acc[i] = 0.f;
    {
        const uint4* p = (const uint4*)(base + n * EMBC + part * 16);
        uint4 r0 = p[0], r1 = p[1];
        unpack8(r0, selfw, acc); unpack8(r1, selfw, acc + 8);
    }
#define LD_G2(s0, s1, J) { int ssrc = s_src[o + (J)]; \
    const uint4* pp = (const uint4*)(base + ssrc * EMBC + part * 16); \
    s0 = pp[0]; s1 = pp[1]; }
    for (int cbase = rs_blk; cbase < re_blk; cbase += CAP) {
        int cnt = min(CAP, re_blk - cbase);
        __syncthreads();
        for (int i = tid; i < cnt; i += 256) {
            s_src[i] = csr_src[cbase + i];
            s_w[i] = csr_norm[cbase + i];
        }
        __syncthreads();
        int a = max(rs, cbase), bb = min(re, cbase + cnt);
        int m = bb - a, o = a - cbase;
        uint4 p00, p01, p10, p11, p20, p21, p30, p31;
        if (m > 0) LD_G2(p00, p01, 0);
        if (m > 1) LD_G2(p10, p11, 1);
        if (m > 2) LD_G2(p20, p21, 2);
        if (m > 3) LD_G2(p30, p31, 3);
        int j = 0;
        while (j + 4 <= m) {
            float w0 = s_w[o + j], w1 = s_w[o + j + 1];
            float w2 = s_w[o + j + 2], w3 = s_w[o + j + 3];
            uint4 c00 = p00, c01 = p01, c10 = p10, c11 = p11;
            uint4 c20 = p20, c21 = p21, c30 = p30, c31 = p31;
            if (j + 4 < m) LD_G2(p00, p01, j + 4);
            if (j + 5 < m) LD_G2(p10, p11, j + 5);
            if (j + 6 < m) LD_G2(p20, p21, j + 6);
            if (j + 7 < m) LD_G2(p30, p31, j + 7);
            unpack8(c00, w0, acc); unpack8(c01, w0, acc + 8);
            unpack8(c10, w1, acc); unpack8(c11, w1, acc + 8);
            unpack8(c20, w2, acc); unpack8(c21, w2, acc + 8);
            unpack8(c30, w3, acc); unpack8(c31, w3, acc + 8);
            j += 4;
        }
        if (j < m) { float w = s_w[o + j]; unpack8(p00, w, acc); unpack8(p01, w, acc + 8); ++j; }
        if (j < m) { float w = s_w[o + j]; unpack8(p10, w, acc); unpack8(p11, w, acc + 8); ++j; }
        if (j < m) { float w = s_w[o + j]; unpack8(p20, w, acc); unpack8(p21, w, acc + 8); ++j; }
    }
#undef LD_G2
    *(uint4*)&sAgg[sub * STRIDE + part * 16] = pack8(acc);
    *(uint4*)&sAgg[sub * STRIDE + part * 16 + 8] = pack8(acc + 8);
    __syncthreads();

    // MFMA (32x128)@(128x128): wave ct -> col tile 32ct
    const int wave = tid >> 6;
    const int lane = tid & 63;
    const int l31 = lane & 31;
    const int q = lane >> 5;
    floatx16 accv = (floatx16)0.f;
#pragma unroll
    for (int kk = 0; kk < 8; ++kk) {
        short8 av = *(const short8*)&sAgg[l31 * STRIDE + kk * 16 + q * 8];
        short8 bb = *(const short8*)(Wt + (size_t)(32 * wave + l31) * EMBC + kk * 16 + q * 8);
        accv = __builtin_amdgcn_mfma_f32_32x32x16_bf16(av, bb, accv, 0, 0, 0);
    }
    __syncthreads();                          // all sAgg reads done
    {
        int col = 32 * wave + l31;
        float bv = bias[col];
#pragma unroll
        for (int r = 0; r < 16; ++r) {
            int row = (r & 3) + 8 * (r >> 2) + 4 * q;
            sAgg[row * STRIDE + col] = f2bf(fmaxf(accv[r] + bv, 0.f));
        }
    }
    __syncthreads();
    // coalesced store: thread -> (node, 16-ch chunk), 32 B each
    {
        const uint4* sp = (const uint4*)&sAgg[(tid >> 3) * STRIDE + (tid & 7) * 16];
        uint4* dp = (uint4*)(h2 + ((size_t)(n0 + (tid >> 3)) * TT + t) * EMBC + (tid & 7) * 16);
        dp[0] = sp[0];
        dp[1] = sp[1];
    }
}

// ---------------------------------------------------------------------------
// conv2 as implicit-im2col 32x32x16 MFMA + bn2 + avgpool4 + relu, fused.
// Block = 2 nodes, 4 waves; A in padded LDS; B double-buffered in LDS.
// ---------------------------------------------------------------------------
__global__ __launch_bounds__(256, 2) void conv2_mfma_kernel(
        const unsigned short* __restrict__ h2, const unsigned short* __restrict__ Bt,
        const float* __restrict__ g2, const float* __restrict__ b2,
        const float* __restrict__ m2, const float* __restrict__ v2,
        float* __restrict__ h3) {
    constexpr int STRIDE = 136;
    constexpr int NODESZ = 70 * STRIDE;
    constexpr int BSLOT = 64 * STRIDE;
    __shared__ __align__(16) unsigned short sA[2 * NODESZ];
    __shared__ __align__(16) unsigned short sB[2 * BSLOT];
    const int tid = threadIdx.x;

    const uint4* src = (const uint4*)(h2 + (size_t)blockIdx.x * 2 * (TT * EMBC));
#pragma unroll
    for (int it = 0; it < 8; ++it) {
        int idx = tid + it * 256;
        int node = idx >> 10;
        int f0 = (idx & 1023) * 8;
        int row = f0 >> 7, col = f0 & 127;
        *(uint4*)&sA[node * NODESZ + row * STRIDE + col] = src[idx];
    }
    if (tid < 192) {
        int node = tid / 96, jj = tid % 96;
        int row = 64 + jj / 16, col = (jj & 15) * 8;
        uint4 z; z.x = z.y = z.z = z.w = 0u;
        *(uint4*)&sA[node * NODESZ + row * STRIDE + col] = z;
    }
    {
        int brow = tid >> 4, bcol = (tid & 15) * 8;
#pragma unroll
        for (int it = 0; it < 4; ++it)
            *(uint4*)&sB[(brow + it * 16) * STRIDE + bcol] =
                *(const uint4*)(Bt + (size_t)(brow + it * 16) * 896 + bcol);
    }
    __syncthreads();

    const int wave = tid >> 6;
    const int lane = tid & 63;
    const int l31 = lane & 31;
    const int q = lane >> 5;
    const int node = wave >> 1;
    const int rh = wave & 1;

    const unsigned short* sAn = &sA[node * NODESZ];
    const int brow = tid >> 4, bcol = (tid & 15) * 8;

    floatx16 acc0 = (floatx16)0.f;
    floatx16 acc1 = (floatx16)0.f;
    uint4 breg[4];

    for (int kw = 0; kw < 7; ++kw) {
        if (kw < 6) {
#pragma unroll
            for (int it = 0; it < 4; ++it)
                breg[it] = *(const uint4*)(Bt + (size_t)(brow + it * 16) * 896 +
                                           (kw + 1) * 128 + bcol);
        }
        const unsigned short* sBc = &sB[(kw & 1) * BSLOT];
#pragma unroll
        for (int kk = 0; kk < 8; ++kk) {
            short8 a = *(const short8*)&sAn[(32 * rh + l31 + kw) * STRIDE + kk * 16 + q * 8];
            short8 b0 = *(const short8*)&sBc[l31 * STRIDE + kk * 16 + q * 8];
            short8 b1 = *(const short8*)&sBc[(32 + l31) * STRIDE + kk * 16 + q * 8];
            acc0 = __builtin_amdgcn_mfma_f32_32x32x16_bf16(a, b0, acc0, 0, 0, 0);
            acc1 = __builtin_amdgcn_mfma_f32_32x32x16_bf16(a, b1, acc1, 0, 0, 0);
        }
        if (kw < 6) {
            unsigned short* sBn = &sB[((kw + 1) & 1) * BSLOT];
#pragma unroll
            for (int it = 0; it < 4; ++it)
                *(uint4*)&sBn[(brow + it * 16) * STRIDE + bcol] = breg[it];
            __syncthreads();
        }
    }
    int n = blockIdx.x * 2 + node;
#pragma unroll
    for (int ct = 0; ct < 2; ++ct) {
        const floatx16& acc = ct ? acc1 : acc0;
        int col = 32 * ct + l31;
        float scale = g2[col] * rsqrtf(v2[col] + BNEPS);
        float mean = m2[col], beta = b2[col];
#pragma unroll
        for (int j = 0; j < 4; ++j) {
            int grp = 2 * j + q + 8 * rh;
            if (grp < 14) {
                float p = 0.25f * (acc[4 * j] + acc[4 * j + 1] + acc[4 * j + 2] + acc[4 * j + 3]);
                float val = (p - mean) * scale + beta;
                h3[((size_t)n * 14 + grp) * K1C + col] = fmaxf(val, 0.f);
            }
        }
    }
}

// ---------------------------------------------------------------------------
// Global mean pool per graph: h3 (N,14,64) -> g1 (B,14,64). batch = n/32.
// ---------------------------------------------------------------------------
__global__ void graph_pool_kernel(const float* __restrict__ h3, float* __restrict__ g1) {
    int b = blockIdx.x;
    for (int i = threadIdx.x; i < 14 * K1C; i += 256) {
        float acc = 0.f;
        for (int nn = 0; nn < 32; ++nn)
            acc += h3[((size_t)(b * 32 + nn)) * (14 * K1C) + i];
        g1[(size_t)b * (14 * K1C) + i] = acc * (1.f / 32.f);
    }
}

// ---------------------------------------------------------------------------
// Head: conv3 + bn3 + pool4 + relu + flatten + dense + log_softmax.
// ---------------------------------------------------------------------------
__global__ __launch_bounds__(256) void head_kernel(
        const float* __restrict__ g1, const float* __restrict__ w3,
        const float* __restrict__ g3, const float* __restrict__ b3,
        const float* __restrict__ m3, const float* __restrict__ v3,
        const float* __restrict__ dw, const float* __restrict__ db,
        float* __restrict__ out) {
    __shared__ float sg[14 * 64];
    __shared__ float sconv[8 * 64];
    __shared__ float sflat[128];
    __shared__ float slog[4];
    int b = blockIdx.x;
    int tid = threadIdx.x;
    for (int i = tid; i < 14 * 64; i += 256) sg[i] = g1[(size_t)b * (14 * 64) + i];
    __syncthreads();
    for (int i = tid; i < 8 * 64; i += 256) {
        int t = i >> 6, c = i & 63;
        float acc = 0.f;
        for (int k = 0; k < KSZ; ++k)
            for (int cin = 0; cin < 64; ++cin)
                acc += sg[(t + k) * 64 + cin] * w3[((size_t)(k * 64 + cin)) * 64 + c];
        sconv[i] = acc;
    }
    __syncthreads();
    for (int i = tid; i < 128; i += 256) {
        int j = i >> 6, c = i & 63;
        float p = 0.25f * (sconv[(4 * j + 0) * 64 + c] + sconv[(4 * j + 1) * 64 + c] +
                           sconv[(4 * j + 2) * 64 + c] + sconv[(4 * j + 3) * 64 + c]);
        float scale = g3[c] * rsqrtf(v3[c] + BNEPS);
        float val = (p - m3[c]) * scale + b3[c];
        sflat[i] = fmaxf(val, 0.f);
    }
    __syncthreads();
    if (tid < 4) {
        float acc = db[tid];
        for (int i = 0; i < 128; ++i) acc += sflat[i] * dw[i * 4 + tid];
        slog[tid] = acc;
    }
    __syncthreads();
    if (tid < 4) {
        float mx = fmaxf(fmaxf(slog[0], slog[1]), fmaxf(slog[2], slog[3]));
        float s = expf(slog[0] - mx) + expf(slog[1] - mx) +
                  expf(slog[2] - mx) + expf(slog[3] - mx);
        out[b * 4 + tid] = slog[tid] - mx - logf(s);
    }
}

// ---------------------------------------------------------------------------
extern "C" void kernel_launch(void* const* d_in, const int* in_sizes, int n_in,
                              void* d_out, int out_size, void* d_ws, size_t ws_size,
                              hipStream_t stream) {
    const float* x       = (const float*)d_in[0];
    const int*   ei      = (const int*)d_in[1];
    // d_in[2] = batch (arange//32, handled analytically)
    const float* conv1_w = (const float*)d_in[3];
    const float* bn1_g   = (const float*)d_in[4];
    const float* bn1_b   = (const float*)d_in[5];
    const float* bn1_m   = (const float*)d_in[6];
    const float* bn1_v   = (const float*)d_in[7];
    const float* gcn1_w  = (const float*)d_in[8];
    const float* gcn1_b  = (const float*)d_in[9];
    const float* gcn2_w  = (const float*)d_in[10];
    const float* gcn2_b  = (const float*)d_in[11];
    const float* conv2_w = (const float*)d_in[12];
    const float* bn2_g   = (const float*)d_in[13];
    const float* bn2_b   = (const float*)d_in[14];
    const float* bn2_m   = (const float*)d_in[15];
    const float* bn2_v   = (const float*)d_in[16];
    const float* conv3_w = (const float*)d_in[17];
    const float* bn3_g   = (const float*)d_in[18];
    const float* bn3_b   = (const float*)d_in[19];
    const float* bn3_m   = (const float*)d_in[20];
    const float* bn3_v   = (const float*)d_in[21];
    const float* dense_w = (const float*)d_in[22];
    const float* dense_b = (const float*)d_in[23];
    float* out = (float*)d_out;

    // Workspace layout (256B-aligned slots)
    char* ws = (char*)d_ws;
    size_t off = 0;
    auto alloc = [&](size_t bytes) { size_t o = off; off += (bytes + 255) & ~(size_t)255; return o; };
    size_t o_counters = alloc(2 * NN * sizeof(int));          // deg | cursor (zeroed)
    size_t o_rowstart = alloc((NN + 1) * sizeof(int));
    size_t o_csrsrc   = alloc(EE * sizeof(int));
    size_t o_csrnorm  = alloc(EE * sizeof(float));
    size_t o_dinv     = alloc(NN * sizeof(float));
    size_t o_wt1      = alloc(4096 * sizeof(unsigned short));
    size_t o_wt2      = alloc(16384 * sizeof(unsigned short));
    size_t o_bt       = alloc(57344 * sizeof(unsigned short));
    size_t o_h0       = alloc((size_t)NN * TT * K0C * sizeof(unsigned short));   // h0t (T,N,32)
    size_t o_h1       = alloc((size_t)NN * TT * EMBC * sizeof(unsigned short));  // h1t (T,N,128)
    size_t o_h2       = alloc((size_t)NN * TT * EMBC * sizeof(unsigned short));  // h2 (N,T,128)
    size_t o_h3       = alloc((size_t)NN * 14 * K1C * sizeof(float));
    size_t o_g1       = alloc((size_t)BB * 14 * K1C * sizeof(float));
    (void)alloc(4096); // slack

    int*   deg_i    = (int*)(ws + o_counters);
    int*   rowstart = (int*)(ws + o_rowstart);
    int*   csr_src  = (int*)(ws + o_csrsrc);
    float* csr_nrm  = (float*)(ws + o_csrnorm);
    float* dinv     = (float*)(ws + o_dinv);
    unsigned short* Wt1 = (unsigned short*)(ws + o_wt1);
    unsigned short* Wt2 = (unsigned short*)(ws + o_wt2);
    unsigned short* Bt  = (unsigned short*)(ws + o_bt);
    unsigned short* h0t = (unsigned short*)(ws + o_h0);
    unsigned short* h1t = (unsigned short*)(ws + o_h1);
    unsigned short* h2  = (unsigned short*)(ws + o_h2);
    float* h3 = (float*)(ws + o_h3);
    float* g1 = (float*)(ws + o_g1);
    int* cursor = deg_i + NN;

    hipMemsetAsync(deg_i, 0, 2 * NN * sizeof(int), stream);

    count_deg_kernel<<<EE / 256, 256, 0, stream>>>(ei, deg_i);
    dinv_kernel<<<NN / 256, 256, 0, stream>>>(deg_i, dinv);
    scan_kernel<<<1, 256, 0, stream>>>(deg_i, rowstart);
    fill_csr_kernel<<<EE / 256, 256, 0, stream>>>(ei, rowstart, cursor, dinv, csr_src, csr_nrm);
    prep_weights_kernel<<<304, 256, 0, stream>>>(gcn1_w, gcn2_w, conv2_w, Wt1, Wt2, Bt);

    conv1_bn_relu_kernel<<<(NN * TT * K0C) / 256, 256, 0, stream>>>(
        x, conv1_w, bn1_g, bn1_b, bn1_m, bn1_v, h0t);

    gcn1_t_kernel<<<64 * 16, 256, 0, stream>>>(h0t, Wt1, gcn1_b, h1t,
                                               rowstart, csr_src, csr_nrm, dinv);
    gcn2_t_kernel<<<64 * 64, 256, 0, stream>>>(h1t, Wt2, gcn2_b, h2,
                                               rowstart, csr_src, csr_nrm, dinv);

    conv2_mfma_kernel<<<NN / 2, 256, 0, stream>>>(h2, Bt, bn2_g, bn2_b, bn2_m, bn2_v, h3);
    graph_pool_kernel<<<BB, 256, 0, stream>>>(h3, g1);
    head_kernel<<<BB, 256, 0, stream>>>(g1, conv3_w, bn3_g, bn3_b, bn3_m, bn3_v,
                                        dense_w, dense_b, out);
}